// Round 3
// baseline (1108.819 us; speedup 1.0000x reference)
//
#include <hip/hip_runtime.h>

#define D 128
#define BM 64
#define BK 32
#define BW_LOG 6          // 64 nodes per bucket
#define BWID 64
#define CAP 4096          // max edges per bucket in LDS (mean ~2046, max ~2300)

// ---------- CSR build via two-level counting sort ----------

__global__ void bucket_hist_kernel(const int* __restrict__ dst, int* __restrict__ bcnt, int n) {
    int i = blockIdx.x * blockDim.x + threadIdx.x;
    if (i < n) atomicAdd(&bcnt[dst[i] >> BW_LOG], 1);
}

// single-wave exclusive scan over nb bucket counts -> bbase[nb+1], bcur (cursor copy), off[N]=E
__global__ void bucket_scan_kernel(const int* __restrict__ bcnt, int* __restrict__ bbase,
                                   int* __restrict__ bcur, int* __restrict__ off_last, int nb) {
    int t = threadIdx.x;          // 64 threads
    int chunk = (nb + 63) >> 6;
    int lo = t * chunk, hi = min(lo + chunk, nb);
    int s = 0;
    for (int i = lo; i < hi; ++i) s += bcnt[i];
    int incl = s;
#pragma unroll
    for (int d2 = 1; d2 < 64; d2 <<= 1) { int u = __shfl_up(incl, d2, 64); if (t >= d2) incl += u; }
    int excl = incl - s;
    for (int i = lo; i < hi; ++i) { int c = bcnt[i]; bbase[i] = excl; bcur[i] = excl; excl += c; }
    if (t == 63) { bbase[nb] = incl; *off_last = incl; }
}

// bin edges into bucket regions; record = (dst_local << 16) | src   (src < 65536)
__global__ void bucket_scatter_kernel(const int* __restrict__ src, const int* __restrict__ dst,
                                      int* __restrict__ bcur, unsigned int* __restrict__ ebuf, int n) {
    int i = blockIdx.x * blockDim.x + threadIdx.x;
    if (i < n) {
        int d = dst[i];
        int p = atomicAdd(&bcur[d >> BW_LOG], 1);
        ebuf[p] = ((unsigned)(d & (BWID - 1)) << 16) | (unsigned)src[i];
    }
}

// one block per bucket: LDS counting sort by dst_local, in-place in ebuf; writes off[]
__global__ __launch_bounds__(256)
void bucket_sort_kernel(unsigned int* __restrict__ ebuf, const int* __restrict__ bbase,
                        int* __restrict__ off, int n_nodes) {
    __shared__ unsigned int in_s[CAP];
    __shared__ unsigned short out_s[CAP];
    __shared__ int hist[BWID], cur[BWID];
    int b = blockIdx.x;
    int base = bbase[b];
    int n_b = bbase[b + 1] - base;
    int t = threadIdx.x;
    if (t < BWID) hist[t] = 0;
    for (int i = t; i < n_b && i < CAP; i += 256) in_s[i] = ebuf[base + i];
    __syncthreads();
    for (int i = t; i < n_b && i < CAP; i += 256) atomicAdd(&hist[in_s[i] >> 16], 1);
    __syncthreads();
    if (t < BWID) {
        int s = hist[t];
        int incl = s;
#pragma unroll
        for (int d2 = 1; d2 < 64; d2 <<= 1) { int u = __shfl_up(incl, d2, 64); if (t >= d2) incl += u; }
        int excl = incl - s;
        cur[t] = excl;
        int node = (b << BW_LOG) + t;
        if (node < n_nodes) off[node] = base + excl;
    }
    __syncthreads();
    for (int i = t; i < n_b && i < CAP; i += 256) {
        unsigned v = in_s[i];
        int p = atomicAdd(&cur[v >> 16], 1);
        if (p < CAP) out_s[p] = (unsigned short)(v & 0xffffu);
    }
    __syncthreads();
    for (int i = t; i < n_b && i < CAP; i += 256) ebuf[base + i] = (unsigned int)out_s[i];
}

// ---------- mean aggregation ----------
// 32 lanes per node (float4/lane covers D=128), edge loop unrolled x8.

__global__ __launch_bounds__(256)
void aggregate_kernel(const float* __restrict__ x, const int* __restrict__ off,
                      const unsigned int* __restrict__ eidx, float* __restrict__ mean,
                      int n_nodes) {
    int node = blockIdx.x * 8 + (threadIdx.x >> 5);
    int lane = threadIdx.x & 31;
    if (node >= n_nodes) return;
    int beg = off[node], end = off[node + 1];
    int c = lane * 4;

    float4 acc = make_float4(0.f, 0.f, 0.f, 0.f);
    int e = beg;
    for (; e + 8 <= end; e += 8) {
        const float4* p0 = (const float4*)&x[(size_t)(eidx[e + 0] & 0xffffu) * D + c];
        const float4* p1 = (const float4*)&x[(size_t)(eidx[e + 1] & 0xffffu) * D + c];
        const float4* p2 = (const float4*)&x[(size_t)(eidx[e + 2] & 0xffffu) * D + c];
        const float4* p3 = (const float4*)&x[(size_t)(eidx[e + 3] & 0xffffu) * D + c];
        const float4* p4 = (const float4*)&x[(size_t)(eidx[e + 4] & 0xffffu) * D + c];
        const float4* p5 = (const float4*)&x[(size_t)(eidx[e + 5] & 0xffffu) * D + c];
        const float4* p6 = (const float4*)&x[(size_t)(eidx[e + 6] & 0xffffu) * D + c];
        const float4* p7 = (const float4*)&x[(size_t)(eidx[e + 7] & 0xffffu) * D + c];
        float4 v0 = *p0, v1 = *p1, v2 = *p2, v3 = *p3;
        float4 v4 = *p4, v5 = *p5, v6 = *p6, v7 = *p7;
        acc.x += v0.x + v1.x + v2.x + v3.x + v4.x + v5.x + v6.x + v7.x;
        acc.y += v0.y + v1.y + v2.y + v3.y + v4.y + v5.y + v6.y + v7.y;
        acc.z += v0.z + v1.z + v2.z + v3.z + v4.z + v5.z + v6.z + v7.z;
        acc.w += v0.w + v1.w + v2.w + v3.w + v4.w + v5.w + v6.w + v7.w;
    }
    for (; e < end; ++e) {
        float4 v = *(const float4*)&x[(size_t)(eidx[e] & 0xffffu) * D + c];
        acc.x += v.x; acc.y += v.y; acc.z += v.z; acc.w += v.w;
    }

    int deg = end - beg;
    float inv = 1.f / (float)(deg > 0 ? deg : 1);
    float4 m = make_float4(acc.x * inv, acc.y * inv, acc.z * inv, acc.w * inv);
    *(float4*)&mean[(size_t)node * D + c] = m;
}

// ---------- fused linear: out = relu([mean||x] @ [Wl||Wr]^T + b) ----------

__global__ __launch_bounds__(256)
void sage_linear_kernel(const float* __restrict__ mean, const float* __restrict__ xin,
                        const float* __restrict__ Wl, const float* __restrict__ Wr,
                        const float* __restrict__ bias, float* __restrict__ out,
                        int n_nodes) {
    __shared__ float As[BM][36];
    __shared__ float Bs[BK][D];

    int t = threadIdx.x;
    int tx = t & 31;
    int ty = t >> 5;
    int row0 = blockIdx.x * BM;

    float acc[8][4] = {};

    for (int kt = 0; kt < 8; ++kt) {
        int kbase = kt * BK;
        const float* Asrc = (kbase < D) ? mean : xin;
        const float* Wsrc = (kbase < D) ? Wl : Wr;
        int ksrc = kbase & (D - 1);

        {
            int r = t >> 2;
            int c = (t & 3) * 8;
            int gr = row0 + r;
            if (gr < n_nodes) {
                const float* p = Asrc + (size_t)gr * D + ksrc + c;
                float4 v0 = *(const float4*)(p);
                float4 v1 = *(const float4*)(p + 4);
                *(float4*)&As[r][c] = v0;
                *(float4*)&As[r][c + 4] = v1;
            } else {
#pragma unroll
                for (int q = 0; q < 8; ++q) As[r][c + q] = 0.f;
            }
        }
        {
            int j = t & 127;
            int kh = (t >> 7) * 16;
            const float* p = Wsrc + (size_t)j * D + ksrc + kh;
#pragma unroll
            for (int q = 0; q < 16; ++q) Bs[kh + q][j] = p[q];
        }
        __syncthreads();

#pragma unroll
        for (int kk = 0; kk < BK; ++kk) {
            float a[8];
#pragma unroll
            for (int r = 0; r < 8; ++r) a[r] = As[ty * 8 + r][kk];
            float4 bv = *(const float4*)&Bs[kk][tx * 4];
#pragma unroll
            for (int r = 0; r < 8; ++r) {
                acc[r][0] += a[r] * bv.x;
                acc[r][1] += a[r] * bv.y;
                acc[r][2] += a[r] * bv.z;
                acc[r][3] += a[r] * bv.w;
            }
        }
        __syncthreads();
    }

    float4 bb = *(const float4*)&bias[tx * 4];
#pragma unroll
    for (int r = 0; r < 8; ++r) {
        int gr = row0 + ty * 8 + r;
        if (gr < n_nodes) {
            float4 o;
            o.x = fmaxf(acc[r][0] + bb.x, 0.f);
            o.y = fmaxf(acc[r][1] + bb.y, 0.f);
            o.z = fmaxf(acc[r][2] + bb.z, 0.f);
            o.w = fmaxf(acc[r][3] + bb.w, 0.f);
            *(float4*)&out[(size_t)gr * D + tx * 4] = o;
        }
    }
}

extern "C" void kernel_launch(void* const* d_in, const int* in_sizes, int n_in,
                              void* d_out, int out_size, void* d_ws, size_t ws_size,
                              hipStream_t stream) {
    const float* x   = (const float*)d_in[0];
    const int*   ei  = (const int*)d_in[1];
    const float* W1l = (const float*)d_in[2];
    const float* W1r = (const float*)d_in[3];
    const float* b1  = (const float*)d_in[4];
    const float* W2l = (const float*)d_in[5];
    const float* W2r = (const float*)d_in[6];
    const float* b2  = (const float*)d_in[7];
    float* out = (float*)d_out;

    const int N = in_sizes[0] / D;
    const int E = in_sizes[1] / 2;
    const int* src = ei;
    const int* dst = ei + E;
    const int NB = (N + BWID - 1) >> BW_LOG;

    // workspace layout (16B-aligned blocks)
    int* off_p   = (int*)d_ws;                         // N+1
    int* bcnt_p  = off_p + ((N + 16) & ~15);           // NB
    int* bbase_p = bcnt_p + ((NB + 16) & ~15);         // NB+1
    int* bcur_p  = bbase_p + ((NB + 16) & ~15);        // NB
    unsigned int* ebuf_p = (unsigned int*)(bcur_p + ((NB + 16) & ~15));  // E
    float* mean_p = (float*)(ebuf_p + ((E + 15) & ~15));                 // N*D

    hipMemsetAsync(bcnt_p, 0, (size_t)NB * sizeof(int), stream);
    bucket_hist_kernel<<<(E + 255) / 256, 256, 0, stream>>>(dst, bcnt_p, E);
    bucket_scan_kernel<<<1, 64, 0, stream>>>(bcnt_p, bbase_p, bcur_p, off_p + N, NB);
    bucket_scatter_kernel<<<(E + 255) / 256, 256, 0, stream>>>(src, dst, bcur_p, ebuf_p, E);
    bucket_sort_kernel<<<NB, 256, 0, stream>>>(ebuf_p, bbase_p, off_p, N);

    // layer 1: h1 -> d_out
    aggregate_kernel<<<(N + 7) / 8, 256, 0, stream>>>(x, off_p, ebuf_p, mean_p, N);
    sage_linear_kernel<<<(N + BM - 1) / BM, 256, 0, stream>>>(mean_p, x, W1l, W1r, b1, out, N);

    // layer 2: in-place on d_out (each block reads only its own rows before writing)
    aggregate_kernel<<<(N + 7) / 8, 256, 0, stream>>>(out, off_p, ebuf_p, mean_p, N);
    sage_linear_kernel<<<(N + BM - 1) / BM, 256, 0, stream>>>(mean_p, out, W2l, W2r, b2, out, N);
}

// Round 4
// 382.550 us; speedup vs baseline: 2.8985x; 2.8985x over previous
//
#include <hip/hip_runtime.h>

#define D 128
#define BM 64
#define BK 32
#define BW_LOG 6          // 64 nodes per bucket
#define BWID 64
#define CAP 4096          // max edges per bucket in LDS (mean ~2046, max ~2350)
#define CHUNK 4096        // edges per partition block
#define NB_MAX 1024       // supports N <= 65536 (also required by 16-bit src packing)

// ---------- CSR build via deterministic two-pass privatized counting sort ----------

// pass A: per-block LDS histogram over buckets -> gh[bucket * nblk + block]
__global__ __launch_bounds__(256)
void part_hist_kernel(const int* __restrict__ dst, int* __restrict__ gh,
                      int E, int nb, int nblk) {
    __shared__ int h[NB_MAX];
    int b = blockIdx.x;
    for (int i = threadIdx.x; i < nb; i += 256) h[i] = 0;
    __syncthreads();
    int lo = b * CHUNK, hi = min(lo + CHUNK, E);
    for (int i = lo + threadIdx.x; i < hi; i += 256) atomicAdd(&h[dst[i] >> BW_LOG], 1);
    __syncthreads();
    for (int i = threadIdx.x; i < nb; i += 256) gh[(size_t)i * nblk + b] = h[i];
}

// pass B1: one wave per bucket, exclusive scan across its nblk entries; total -> btot
__global__ __launch_bounds__(64)
void part_scan1_kernel(int* __restrict__ gh, int* __restrict__ btot, int nblk) {
    int k = blockIdx.x;
    int t = threadIdx.x;
    int* row = gh + (size_t)k * nblk;
    int chunk = (nblk + 63) >> 6;
    int lo = t * chunk, hi = min(lo + chunk, nblk);
    int s = 0;
    for (int i = lo; i < hi; ++i) s += row[i];
    int incl = s;
#pragma unroll
    for (int d2 = 1; d2 < 64; d2 <<= 1) { int u = __shfl_up(incl, d2, 64); if (t >= d2) incl += u; }
    int excl = incl - s;
    for (int i = lo; i < hi; ++i) { int c = row[i]; row[i] = excl; excl += c; }
    if (t == 63) btot[k] = incl;
}

// pass B2: single block scans nb bucket totals -> bbase[nb+1]; off[N] = E
__global__ __launch_bounds__(1024)
void part_scan2_kernel(const int* __restrict__ btot, int* __restrict__ bbase,
                       int nb, int* __restrict__ offN) {
    __shared__ int ws[16];
    int t = threadIdx.x, lane = t & 63, wid = t >> 6;
    int v = (t < nb) ? btot[t] : 0;
    int incl = v;
#pragma unroll
    for (int d2 = 1; d2 < 64; d2 <<= 1) { int u = __shfl_up(incl, d2, 64); if (lane >= d2) incl += u; }
    if (lane == 63) ws[wid] = incl;
    __syncthreads();
    if (wid == 0) {
        int w = (lane < 16) ? ws[lane] : 0;
#pragma unroll
        for (int d2 = 1; d2 < 16; d2 <<= 1) { int u = __shfl_up(w, d2, 64); if (lane >= d2) w += u; }
        if (lane < 16) ws[lane] = w;
    }
    __syncthreads();
    int base = wid ? ws[wid - 1] : 0;
    int excl = base + incl - v;
    if (t < nb) bbase[t] = excl;
    if (t == nb - 1) { bbase[nb] = excl + v; *offN = excl + v; }
}

// pass C: re-read edges, place via LDS cursors (no global atomics)
// record = (dst_local << 16) | src   (src < 65536)
__global__ __launch_bounds__(256)
void part_scatter_kernel(const int* __restrict__ src, const int* __restrict__ dst,
                         const int* __restrict__ gh, const int* __restrict__ bbase,
                         unsigned int* __restrict__ ebuf, int E, int nb, int nblk) {
    __shared__ int cur[NB_MAX];
    int b = blockIdx.x;
    for (int i = threadIdx.x; i < nb; i += 256)
        cur[i] = bbase[i] + gh[(size_t)i * nblk + b];
    __syncthreads();
    int lo = b * CHUNK, hi = min(lo + CHUNK, E);
    for (int i = lo + threadIdx.x; i < hi; i += 256) {
        int d = dst[i];
        int p = atomicAdd(&cur[d >> BW_LOG], 1);
        ebuf[p] = ((unsigned)(d & (BWID - 1)) << 16) | (unsigned)src[i];
    }
}

// one block per bucket: LDS counting sort by dst_local, in-place in ebuf; writes off[]
__global__ __launch_bounds__(256)
void bucket_sort_kernel(unsigned int* __restrict__ ebuf, const int* __restrict__ bbase,
                        int* __restrict__ off, int n_nodes) {
    __shared__ unsigned int in_s[CAP];
    __shared__ unsigned short out_s[CAP];
    __shared__ int hist[BWID], cur[BWID];
    int b = blockIdx.x;
    int base = bbase[b];
    int n_b = bbase[b + 1] - base;
    int t = threadIdx.x;
    if (t < BWID) hist[t] = 0;
    for (int i = t; i < n_b && i < CAP; i += 256) in_s[i] = ebuf[base + i];
    __syncthreads();
    for (int i = t; i < n_b && i < CAP; i += 256) atomicAdd(&hist[in_s[i] >> 16], 1);
    __syncthreads();
    if (t < BWID) {
        int s = hist[t];
        int incl = s;
#pragma unroll
        for (int d2 = 1; d2 < 64; d2 <<= 1) { int u = __shfl_up(incl, d2, 64); if (t >= d2) incl += u; }
        int excl = incl - s;
        cur[t] = excl;
        int node = (b << BW_LOG) + t;
        if (node < n_nodes) off[node] = base + excl;
    }
    __syncthreads();
    for (int i = t; i < n_b && i < CAP; i += 256) {
        unsigned v = in_s[i];
        int p = atomicAdd(&cur[v >> 16], 1);
        if (p < CAP) out_s[p] = (unsigned short)(v & 0xffffu);
    }
    __syncthreads();
    for (int i = t; i < n_b && i < CAP; i += 256) ebuf[base + i] = (unsigned int)out_s[i];
}

// ---------- mean aggregation ----------
// 32 lanes per node (float4/lane covers D=128), edge loop unrolled x8.

__global__ __launch_bounds__(256)
void aggregate_kernel(const float* __restrict__ x, const int* __restrict__ off,
                      const unsigned int* __restrict__ eidx, float* __restrict__ mean,
                      int n_nodes) {
    int node = blockIdx.x * 8 + (threadIdx.x >> 5);
    int lane = threadIdx.x & 31;
    if (node >= n_nodes) return;
    int beg = off[node], end = off[node + 1];
    int c = lane * 4;

    float4 acc = make_float4(0.f, 0.f, 0.f, 0.f);
    int e = beg;
    for (; e + 8 <= end; e += 8) {
        const float4* p0 = (const float4*)&x[(size_t)(eidx[e + 0] & 0xffffu) * D + c];
        const float4* p1 = (const float4*)&x[(size_t)(eidx[e + 1] & 0xffffu) * D + c];
        const float4* p2 = (const float4*)&x[(size_t)(eidx[e + 2] & 0xffffu) * D + c];
        const float4* p3 = (const float4*)&x[(size_t)(eidx[e + 3] & 0xffffu) * D + c];
        const float4* p4 = (const float4*)&x[(size_t)(eidx[e + 4] & 0xffffu) * D + c];
        const float4* p5 = (const float4*)&x[(size_t)(eidx[e + 5] & 0xffffu) * D + c];
        const float4* p6 = (const float4*)&x[(size_t)(eidx[e + 6] & 0xffffu) * D + c];
        const float4* p7 = (const float4*)&x[(size_t)(eidx[e + 7] & 0xffffu) * D + c];
        float4 v0 = *p0, v1 = *p1, v2 = *p2, v3 = *p3;
        float4 v4 = *p4, v5 = *p5, v6 = *p6, v7 = *p7;
        acc.x += v0.x + v1.x + v2.x + v3.x + v4.x + v5.x + v6.x + v7.x;
        acc.y += v0.y + v1.y + v2.y + v3.y + v4.y + v5.y + v6.y + v7.y;
        acc.z += v0.z + v1.z + v2.z + v3.z + v4.z + v5.z + v6.z + v7.z;
        acc.w += v0.w + v1.w + v2.w + v3.w + v4.w + v5.w + v6.w + v7.w;
    }
    for (; e < end; ++e) {
        float4 v = *(const float4*)&x[(size_t)(eidx[e] & 0xffffu) * D + c];
        acc.x += v.x; acc.y += v.y; acc.z += v.z; acc.w += v.w;
    }

    int deg = end - beg;
    float inv = 1.f / (float)(deg > 0 ? deg : 1);
    float4 m = make_float4(acc.x * inv, acc.y * inv, acc.z * inv, acc.w * inv);
    *(float4*)&mean[(size_t)node * D + c] = m;
}

// ---------- fused linear: out = relu([mean||x] @ [Wl||Wr]^T + b) ----------

__global__ __launch_bounds__(256)
void sage_linear_kernel(const float* __restrict__ mean, const float* __restrict__ xin,
                        const float* __restrict__ Wl, const float* __restrict__ Wr,
                        const float* __restrict__ bias, float* __restrict__ out,
                        int n_nodes) {
    __shared__ float As[BM][36];
    __shared__ float Bs[BK][D];

    int t = threadIdx.x;
    int tx = t & 31;
    int ty = t >> 5;
    int row0 = blockIdx.x * BM;

    float acc[8][4] = {};

    for (int kt = 0; kt < 8; ++kt) {
        int kbase = kt * BK;
        const float* Asrc = (kbase < D) ? mean : xin;
        const float* Wsrc = (kbase < D) ? Wl : Wr;
        int ksrc = kbase & (D - 1);

        {
            int r = t >> 2;
            int c = (t & 3) * 8;
            int gr = row0 + r;
            if (gr < n_nodes) {
                const float* p = Asrc + (size_t)gr * D + ksrc + c;
                float4 v0 = *(const float4*)(p);
                float4 v1 = *(const float4*)(p + 4);
                *(float4*)&As[r][c] = v0;
                *(float4*)&As[r][c + 4] = v1;
            } else {
#pragma unroll
                for (int q = 0; q < 8; ++q) As[r][c + q] = 0.f;
            }
        }
        {
            int j = t & 127;
            int kh = (t >> 7) * 16;
            const float* p = Wsrc + (size_t)j * D + ksrc + kh;
#pragma unroll
            for (int q = 0; q < 16; ++q) Bs[kh + q][j] = p[q];
        }
        __syncthreads();

#pragma unroll
        for (int kk = 0; kk < BK; ++kk) {
            float a[8];
#pragma unroll
            for (int r = 0; r < 8; ++r) a[r] = As[ty * 8 + r][kk];
            float4 bv = *(const float4*)&Bs[kk][tx * 4];
#pragma unroll
            for (int r = 0; r < 8; ++r) {
                acc[r][0] += a[r] * bv.x;
                acc[r][1] += a[r] * bv.y;
                acc[r][2] += a[r] * bv.z;
                acc[r][3] += a[r] * bv.w;
            }
        }
        __syncthreads();
    }

    float4 bb = *(const float4*)&bias[tx * 4];
#pragma unroll
    for (int r = 0; r < 8; ++r) {
        int gr = row0 + ty * 8 + r;
        if (gr < n_nodes) {
            float4 o;
            o.x = fmaxf(acc[r][0] + bb.x, 0.f);
            o.y = fmaxf(acc[r][1] + bb.y, 0.f);
            o.z = fmaxf(acc[r][2] + bb.z, 0.f);
            o.w = fmaxf(acc[r][3] + bb.w, 0.f);
            *(float4*)&out[(size_t)gr * D + tx * 4] = o;
        }
    }
}

extern "C" void kernel_launch(void* const* d_in, const int* in_sizes, int n_in,
                              void* d_out, int out_size, void* d_ws, size_t ws_size,
                              hipStream_t stream) {
    const float* x   = (const float*)d_in[0];
    const int*   ei  = (const int*)d_in[1];
    const float* W1l = (const float*)d_in[2];
    const float* W1r = (const float*)d_in[3];
    const float* b1  = (const float*)d_in[4];
    const float* W2l = (const float*)d_in[5];
    const float* W2r = (const float*)d_in[6];
    const float* b2  = (const float*)d_in[7];
    float* out = (float*)d_out;

    const int N = in_sizes[0] / D;
    const int E = in_sizes[1] / 2;
    const int* src = ei;
    const int* dst = ei + E;
    const int NB = (N + BWID - 1) >> BW_LOG;       // 782 for N=50000 (must be <= NB_MAX)
    const int NBLK = (E + CHUNK - 1) / CHUNK;      // 391 for E=1.6M

    // workspace layout (16B-aligned blocks)
    int* off_p   = (int*)d_ws;                               // N+1
    int* bbase_p = off_p + ((N + 16) & ~15);                 // NB+1
    int* btot_p  = bbase_p + ((NB + 16) & ~15);              // NB
    int* gh_p    = btot_p + ((NB + 16) & ~15);               // NB*NBLK
    unsigned int* ebuf_p = (unsigned int*)(gh_p + (((size_t)NB * NBLK + 15) & ~15)); // E
    float* mean_p = (float*)(ebuf_p + ((E + 15) & ~15));     // N*D

    part_hist_kernel<<<NBLK, 256, 0, stream>>>(dst, gh_p, E, NB, NBLK);
    part_scan1_kernel<<<NB, 64, 0, stream>>>(gh_p, btot_p, NBLK);
    part_scan2_kernel<<<1, 1024, 0, stream>>>(btot_p, bbase_p, NB, off_p + N);
    part_scatter_kernel<<<NBLK, 256, 0, stream>>>(src, dst, gh_p, bbase_p, ebuf_p, E, NB, NBLK);
    bucket_sort_kernel<<<NB, 256, 0, stream>>>(ebuf_p, bbase_p, off_p, N);

    // layer 1: h1 -> d_out
    aggregate_kernel<<<(N + 7) / 8, 256, 0, stream>>>(x, off_p, ebuf_p, mean_p, N);
    sage_linear_kernel<<<(N + BM - 1) / BM, 256, 0, stream>>>(mean_p, x, W1l, W1r, b1, out, N);

    // layer 2: in-place on d_out (each block reads only its own rows before writing)
    aggregate_kernel<<<(N + 7) / 8, 256, 0, stream>>>(out, off_p, ebuf_p, mean_p, N);
    sage_linear_kernel<<<(N + BM - 1) / BM, 256, 0, stream>>>(mean_p, out, W2l, W2r, b2, out, N);
}

// Round 5
// 232.916 us; speedup vs baseline: 4.7606x; 1.6424x over previous
//
#include <hip/hip_runtime.h>

#define D 128
#define BW_LOG 6          // 64 nodes per bucket
#define BWID 64
#define CAP 4096          // max edges per bucket in LDS (mean ~2048, max ~2350)
#define CHUNK 8192        // edges per partition block
#define NB_MAX 1024       // supports N <= 65536 (also required by 16-bit src packing)

typedef unsigned short u16;
typedef unsigned int u32;
typedef __attribute__((ext_vector_type(8))) short bf16x8;   // 8 bf16 (4 VGPRs)
typedef __attribute__((ext_vector_type(4))) float f32x4;

__device__ __forceinline__ float bf2f(u16 h) { return __uint_as_float(((u32)h) << 16); }
__device__ __forceinline__ u16 f2bf(float f) {
    u32 u = __float_as_uint(f);
    u32 r = (u + 0x7fffu + ((u >> 16) & 1u)) >> 16;   // RNE
    return (u16)r;
}

// ---------- dtype conversion ----------

__global__ __launch_bounds__(256)
void cvt_x_kernel(const float* __restrict__ x, u16* __restrict__ xb, int n4) {
    int i = blockIdx.x * 256 + threadIdx.x;
    if (i < n4) {
        float4 v = ((const float4*)x)[i];
        ushort4 o;
        o.x = f2bf(v.x); o.y = f2bf(v.y); o.z = f2bf(v.z); o.w = f2bf(v.w);
        ((ushort4*)xb)[i] = o;
    }
}

// wcat[n][k], k<128 from Wl[n][k], else Wr[n][k-128]; 128 blocks x 256 threads
__global__ __launch_bounds__(256)
void cvt_w_kernel(const float* __restrict__ Wl, const float* __restrict__ Wr,
                  u16* __restrict__ wcat) {
    int n = blockIdx.x, k = threadIdx.x;
    float v = (k < 128) ? Wl[n * 128 + k] : Wr[n * 128 + k - 128];
    wcat[n * 256 + k] = f2bf(v);
}

// ---------- CSR build via deterministic two-pass privatized counting sort ----------

__global__ __launch_bounds__(256)
void part_hist_kernel(const int* __restrict__ dst, int* __restrict__ gh,
                      int E, int nb, int nblk) {
    __shared__ int h[NB_MAX];
    int b = blockIdx.x;
    for (int i = threadIdx.x; i < nb; i += 256) h[i] = 0;
    __syncthreads();
    int lo = b * CHUNK, hi = min(lo + CHUNK, E);
    for (int i = lo + threadIdx.x; i < hi; i += 256) atomicAdd(&h[dst[i] >> BW_LOG], 1);
    __syncthreads();
    for (int i = threadIdx.x; i < nb; i += 256) gh[(size_t)i * nblk + b] = h[i];
}

__global__ __launch_bounds__(64)
void part_scan1_kernel(int* __restrict__ gh, int* __restrict__ btot, int nblk) {
    int k = blockIdx.x;
    int t = threadIdx.x;
    int* row = gh + (size_t)k * nblk;
    int chunk = (nblk + 63) >> 6;
    int lo = t * chunk, hi = min(lo + chunk, nblk);
    int s = 0;
    for (int i = lo; i < hi; ++i) s += row[i];
    int incl = s;
#pragma unroll
    for (int d2 = 1; d2 < 64; d2 <<= 1) { int u = __shfl_up(incl, d2, 64); if (t >= d2) incl += u; }
    int excl = incl - s;
    for (int i = lo; i < hi; ++i) { int c = row[i]; row[i] = excl; excl += c; }
    if (t == 63) btot[k] = incl;
}

__global__ __launch_bounds__(1024)
void part_scan2_kernel(const int* __restrict__ btot, int* __restrict__ bbase,
                       int nb, int* __restrict__ offN) {
    __shared__ int ws[16];
    int t = threadIdx.x, lane = t & 63, wid = t >> 6;
    int v = (t < nb) ? btot[t] : 0;
    int incl = v;
#pragma unroll
    for (int d2 = 1; d2 < 64; d2 <<= 1) { int u = __shfl_up(incl, d2, 64); if (lane >= d2) incl += u; }
    if (lane == 63) ws[wid] = incl;
    __syncthreads();
    if (wid == 0) {
        int w = (lane < 16) ? ws[lane] : 0;
#pragma unroll
        for (int d2 = 1; d2 < 16; d2 <<= 1) { int u = __shfl_up(w, d2, 64); if (lane >= d2) w += u; }
        if (lane < 16) ws[lane] = w;
    }
    __syncthreads();
    int base = wid ? ws[wid - 1] : 0;
    int excl = base + incl - v;
    if (t < nb) bbase[t] = excl;
    if (t == nb - 1) { bbase[nb] = excl + v; *offN = excl + v; }
}

// record = (dst_local << 16) | src   (src < 65536)
__global__ __launch_bounds__(256)
void part_scatter_kernel(const int* __restrict__ src, const int* __restrict__ dst,
                         const int* __restrict__ gh, const int* __restrict__ bbase,
                         u32* __restrict__ ebuf, int E, int nb, int nblk) {
    __shared__ int cur[NB_MAX];
    int b = blockIdx.x;
    for (int i = threadIdx.x; i < nb; i += 256)
        cur[i] = bbase[i] + gh[(size_t)i * nblk + b];
    __syncthreads();
    int lo = b * CHUNK, hi = min(lo + CHUNK, E);
    for (int i = lo + threadIdx.x; i < hi; i += 256) {
        int d = dst[i];
        int p = atomicAdd(&cur[d >> BW_LOG], 1);
        ebuf[p] = ((u32)(d & (BWID - 1)) << 16) | (u32)src[i];
    }
}

__global__ __launch_bounds__(256)
void bucket_sort_kernel(u32* __restrict__ ebuf, const int* __restrict__ bbase,
                        int* __restrict__ off, int n_nodes) {
    __shared__ u32 in_s[CAP];
    __shared__ u16 out_s[CAP];
    __shared__ int hist[BWID], cur[BWID];
    int b = blockIdx.x;
    int base = bbase[b];
    int n_b = bbase[b + 1] - base;
    int t = threadIdx.x;
    if (t < BWID) hist[t] = 0;
    for (int i = t; i < n_b && i < CAP; i += 256) in_s[i] = ebuf[base + i];
    __syncthreads();
    for (int i = t; i < n_b && i < CAP; i += 256) atomicAdd(&hist[in_s[i] >> 16], 1);
    __syncthreads();
    if (t < BWID) {
        int s = hist[t];
        int incl = s;
#pragma unroll
        for (int d2 = 1; d2 < 64; d2 <<= 1) { int u = __shfl_up(incl, d2, 64); if (t >= d2) incl += u; }
        int excl = incl - s;
        cur[t] = excl;
        int node = (b << BW_LOG) + t;
        if (node < n_nodes) off[node] = base + excl;
    }
    __syncthreads();
    for (int i = t; i < n_b && i < CAP; i += 256) {
        u32 v = in_s[i];
        int p = atomicAdd(&cur[v >> 16], 1);
        if (p < CAP) out_s[p] = (u16)(v & 0xffffu);
    }
    __syncthreads();
    for (int i = t; i < n_b && i < CAP; i += 256) ebuf[base + i] = (u32)out_s[i];
}

// ---------- mean aggregation over bf16 rows ----------
// 32 lanes per node (ushort4/lane covers D=128), edge loop unrolled x8, fp32 acc, bf16 out.

__global__ __launch_bounds__(256)
void aggregate_bf16_kernel(const u16* __restrict__ xb, const int* __restrict__ off,
                           const u32* __restrict__ eidx, u16* __restrict__ meanb,
                           int n_nodes) {
    int node = blockIdx.x * 8 + (threadIdx.x >> 5);
    int lane = threadIdx.x & 31;
    if (node >= n_nodes) return;
    int beg = off[node], end = off[node + 1];
    int c = lane * 4;

    float ax = 0.f, ay = 0.f, az = 0.f, aw = 0.f;
    int e = beg;
    for (; e + 8 <= end; e += 8) {
        ushort4 v0 = *(const ushort4*)&xb[(size_t)eidx[e + 0] * D + c];
        ushort4 v1 = *(const ushort4*)&xb[(size_t)eidx[e + 1] * D + c];
        ushort4 v2 = *(const ushort4*)&xb[(size_t)eidx[e + 2] * D + c];
        ushort4 v3 = *(const ushort4*)&xb[(size_t)eidx[e + 3] * D + c];
        ushort4 v4 = *(const ushort4*)&xb[(size_t)eidx[e + 4] * D + c];
        ushort4 v5 = *(const ushort4*)&xb[(size_t)eidx[e + 5] * D + c];
        ushort4 v6 = *(const ushort4*)&xb[(size_t)eidx[e + 6] * D + c];
        ushort4 v7 = *(const ushort4*)&xb[(size_t)eidx[e + 7] * D + c];
        ax += bf2f(v0.x) + bf2f(v1.x) + bf2f(v2.x) + bf2f(v3.x)
            + bf2f(v4.x) + bf2f(v5.x) + bf2f(v6.x) + bf2f(v7.x);
        ay += bf2f(v0.y) + bf2f(v1.y) + bf2f(v2.y) + bf2f(v3.y)
            + bf2f(v4.y) + bf2f(v5.y) + bf2f(v6.y) + bf2f(v7.y);
        az += bf2f(v0.z) + bf2f(v1.z) + bf2f(v2.z) + bf2f(v3.z)
            + bf2f(v4.z) + bf2f(v5.z) + bf2f(v6.z) + bf2f(v7.z);
        aw += bf2f(v0.w) + bf2f(v1.w) + bf2f(v2.w) + bf2f(v3.w)
            + bf2f(v4.w) + bf2f(v5.w) + bf2f(v6.w) + bf2f(v7.w);
    }
    for (; e < end; ++e) {
        ushort4 v = *(const ushort4*)&xb[(size_t)eidx[e] * D + c];
        ax += bf2f(v.x); ay += bf2f(v.y); az += bf2f(v.z); aw += bf2f(v.w);
    }

    int deg = end - beg;
    float inv = 1.f / (float)(deg > 0 ? deg : 1);
    ushort4 o;
    o.x = f2bf(ax * inv); o.y = f2bf(ay * inv); o.z = f2bf(az * inv); o.w = f2bf(aw * inv);
    *(ushort4*)&meanb[(size_t)node * D + c] = o;
}

// ---------- fused linear via MFMA: out = relu([mean||self] @ Wcat^T + b) ----------
// 4 waves/block, each wave a 16-row tile. A-frags (8x bf16x8) in registers, reused
// across 8 n-tiles; B-frags direct from L2-hot 64KB Wcat.
// mfma_f32_16x16x32_bf16: A row=l&15 k=(l>>4)*8+j ; C/D col=l&15 row=(l>>4)*4+reg (m89).

template<bool OUT_BF16>
__global__ __launch_bounds__(256)
void linear_mfma_kernel(const u16* __restrict__ Amean, const u16* __restrict__ Aself,
                        const u16* __restrict__ Wc, const float* __restrict__ bias,
                        void* __restrict__ outp, int N) {
    int l = threadIdx.x & 63;
    int wv = threadIdx.x >> 6;
    int m0 = blockIdx.x * 64 + wv * 16;
    int lr = l & 15;
    int kg = (l >> 4) * 8;
    int rowA = m0 + lr;
    int rc = rowA < N ? rowA : N - 1;
    const u16* r1 = Amean + (size_t)rc * D;
    const u16* r2 = Aself + (size_t)rc * D;

    bf16x8 a[8];
#pragma unroll
    for (int kt = 0; kt < 4; ++kt) {
        a[kt]     = *(const bf16x8*)(r1 + kt * 32 + kg);
        a[kt + 4] = *(const bf16x8*)(r2 + kt * 32 + kg);
    }

#pragma unroll
    for (int nt = 0; nt < 8; ++nt) {
        const u16* wp = Wc + (size_t)(nt * 16 + lr) * 256 + kg;
        f32x4 acc = {0.f, 0.f, 0.f, 0.f};
#pragma unroll
        for (int kt = 0; kt < 8; ++kt) {
            bf16x8 b = *(const bf16x8*)(wp + kt * 32);
            acc = __builtin_amdgcn_mfma_f32_16x16x32_bf16(a[kt], b, acc, 0, 0, 0);
        }
        int col = nt * 16 + lr;
        float bb = bias[col];
#pragma unroll
        for (int j = 0; j < 4; ++j) {
            int r = m0 + (l >> 4) * 4 + j;
            if (r < N) {
                float v = fmaxf(acc[j] + bb, 0.f);
                if (OUT_BF16) ((u16*)outp)[(size_t)r * D + col] = f2bf(v);
                else          ((float*)outp)[(size_t)r * D + col] = v;
            }
        }
    }
}

extern "C" void kernel_launch(void* const* d_in, const int* in_sizes, int n_in,
                              void* d_out, int out_size, void* d_ws, size_t ws_size,
                              hipStream_t stream) {
    const float* x   = (const float*)d_in[0];
    const int*   ei  = (const int*)d_in[1];
    const float* W1l = (const float*)d_in[2];
    const float* W1r = (const float*)d_in[3];
    const float* b1  = (const float*)d_in[4];
    const float* W2l = (const float*)d_in[5];
    const float* W2r = (const float*)d_in[6];
    const float* b2  = (const float*)d_in[7];
    float* out = (float*)d_out;

    const int N = in_sizes[0] / D;
    const int E = in_sizes[1] / 2;
    const int* src = ei;
    const int* dst = ei + E;
    const int NB = (N + BWID - 1) >> BW_LOG;       // 782 for N=50000 (<= NB_MAX)
    const int NBLK = (E + CHUNK - 1) / CHUNK;      // 196 for E=1.6M

    // workspace layout, 64B-aligned blocks
    char* wp_ = (char*)d_ws;
    auto alloc = [&](size_t bytes) { char* p = wp_; wp_ += (bytes + 63) & ~(size_t)63; return p; };
    int* off_p   = (int*)alloc((size_t)(N + 1) * 4);
    int* bbase_p = (int*)alloc((size_t)(NB + 1) * 4);
    int* btot_p  = (int*)alloc((size_t)NB * 4);
    int* gh_p    = (int*)alloc((size_t)NB * NBLK * 4);
    u32* ebuf_p  = (u32*)alloc((size_t)E * 4);
    u16* xb      = (u16*)alloc((size_t)N * D * 2);
    u16* meanb   = (u16*)alloc((size_t)N * D * 2);
    u16* h1b     = (u16*)alloc((size_t)N * D * 2);
    u16* wc1     = (u16*)alloc((size_t)128 * 256 * 2);
    u16* wc2     = (u16*)alloc((size_t)128 * 256 * 2);

    // conversions
    cvt_x_kernel<<<(N * D / 4 + 255) / 256, 256, 0, stream>>>(x, xb, N * D / 4);
    cvt_w_kernel<<<128, 256, 0, stream>>>(W1l, W1r, wc1);
    cvt_w_kernel<<<128, 256, 0, stream>>>(W2l, W2r, wc2);

    // CSR build
    part_hist_kernel<<<NBLK, 256, 0, stream>>>(dst, gh_p, E, NB, NBLK);
    part_scan1_kernel<<<NB, 64, 0, stream>>>(gh_p, btot_p, NBLK);
    part_scan2_kernel<<<1, 1024, 0, stream>>>(btot_p, bbase_p, NB, off_p + N);
    part_scatter_kernel<<<NBLK, 256, 0, stream>>>(src, dst, gh_p, bbase_p, ebuf_p, E, NB, NBLK);
    bucket_sort_kernel<<<NB, 256, 0, stream>>>(ebuf_p, bbase_p, off_p, N);

    // layer 1
    aggregate_bf16_kernel<<<(N + 7) / 8, 256, 0, stream>>>(xb, off_p, ebuf_p, meanb, N);
    linear_mfma_kernel<true><<<(N + 63) / 64, 256, 0, stream>>>(meanb, xb, wc1, b1, h1b, N);

    // layer 2
    aggregate_bf16_kernel<<<(N + 7) / 8, 256, 0, stream>>>(h1b, off_p, ebuf_p, meanb, N);
    linear_mfma_kernel<false><<<(N + 63) / 64, 256, 0, stream>>>(meanb, h1b, wc2, b2, out, N);
}